// Round 1
// baseline (151.249 us; speedup 1.0000x reference)
//
#include <hip/hip_runtime.h>
#include <math.h>

// Problem constants (from reference): D=8, H=64, W=64 -> 32768 pixels, 1024 gaussians
#define NG    1024
#define KD    256        // representation feature dim
#define NPIX  32768      // D*H*W
#define BLOCK 512
#define PT    64         // NPIX / BLOCK pixels per thread

// 1.5 * ln(2*pi)
#define C_15_LOG2PI 2.7568155996140185f

__device__ __forceinline__ float softplus_f(float x) {
    // stable: max(x,0) + log1p(exp(-|x|)) — matches jax.nn.softplus
    return fmaxf(x, 0.0f) + log1pf(expf(-fabsf(x)));
}

__global__ __launch_bounds__(BLOCK)
void mvn_profile_kernel(const float* __restrict__ rep,
                        const float* __restrict__ mean_W,
                        const float* __restrict__ mean_b,
                        const float* __restrict__ scale_W,
                        const float* __restrict__ scale_b,
                        float* __restrict__ out)
{
    const int g = blockIdx.x;   // one block per gaussian
    const int t = threadIdx.x;

    __shared__ float s_part[9][4];  // per-wave partials for the 9 dot products
    __shared__ float s_par[10];     // broadcast: mx,my,mz, r00,L10,r11,L20,L21,r22, c
    __shared__ float s_red[8];      // per-wave reduction scratch (8 waves)

    // ---- prelude: 9 dot-products of length 256 (threads 0..255 = waves 0..3) ----
    if (t < KD) {
        float r = rep[g * KD + t];
        float acc[9];
        #pragma unroll
        for (int k = 0; k < 3; ++k) acc[k]     = r * mean_W[k * KD + t];
        #pragma unroll
        for (int k = 0; k < 6; ++k) acc[3 + k] = r * scale_W[k * KD + t];
        #pragma unroll
        for (int k = 0; k < 9; ++k) {
            float v = acc[k];
            #pragma unroll
            for (int off = 32; off >= 1; off >>= 1)
                v += __shfl_xor(v, off, 64);
            if ((t & 63) == 0) s_part[k][t >> 6] = v;
        }
    }
    __syncthreads();
    if (t == 0) {
        float dsum[9];
        #pragma unroll
        for (int k = 0; k < 9; ++k)
            dsum[k] = (s_part[k][0] + s_part[k][1]) + (s_part[k][2] + s_part[k][3]);
        float mx = dsum[0] + mean_b[0];
        float my = dsum[1] + mean_b[1];
        float mz = dsum[2] + mean_b[2];
        float s0 = softplus_f(dsum[3] + scale_b[0]) + 1e-6f;
        float s1 = softplus_f(dsum[4] + scale_b[1]) + 1e-6f;
        float s2 = softplus_f(dsum[5] + scale_b[2]) + 1e-6f;
        float s3 = softplus_f(dsum[6] + scale_b[3]) + 1e-6f;
        float s4 = softplus_f(dsum[7] + scale_b[4]) + 1e-6f;
        float s5 = softplus_f(dsum[8] + scale_b[5]) + 1e-6f;
        float L00 = softplus_f(s0);
        float L11 = softplus_f(s2);
        float L22 = softplus_f(s5);
        s_par[0] = mx; s_par[1] = my; s_par[2] = mz;
        s_par[3] = 1.0f / L00;
        s_par[4] = s1;                // L10
        s_par[5] = 1.0f / L11;
        s_par[6] = s3;                // L20
        s_par[7] = s4;                // L21
        s_par[8] = 1.0f / L22;
        s_par[9] = logf(L00) + logf(L11) + logf(L22) + C_15_LOG2PI;
    }
    __syncthreads();
    const float mx  = s_par[0], my  = s_par[1], mz  = s_par[2];
    const float r00 = s_par[3], L10 = s_par[4], r11 = s_par[5];
    const float L20 = s_par[6], L21 = s_par[7], r22 = s_par[8];
    const float c   = s_par[9];

    // ---- thread-constant x-part: pixel p = t + 512*i -> x index = t & 63 fixed ----
    const float px    = (float)(t & 63) - 31.5f;
    const float y0    = (px - mx) * r00;
    const float negc2 = -(c + 0.5f * y0 * y0);        // folds y0^2 into the constant
    const float dyoff = -31.5f - my - L10 * y0;       // y1 = (fy + dyoff) * r11
    const float dzoff = -3.5f  - mz - L20 * y0;       // y2 = (fz + dzoff - L21*y1) * r22

    // ---- pass A: log-probs in registers, track max ----
    float lp[PT];
    float lmax = -3.4e38f;
    const int jbase = t >> 6;      // 0..7; j = p/64 = jbase + 8*i
    #pragma unroll
    for (int i = 0; i < PT; ++i) {
        int   j  = jbase + 8 * i;          // 0..511
        float fy = (float)(j & 63);
        float fz = (float)(j >> 6);
        float y1 = (fy + dyoff) * r11;
        float w  = fz + dzoff - L21 * y1;
        float y2 = w * r22;
        float q  = y1 * y1 + y2 * y2;
        float v  = fmaf(-0.5f, q, negc2);
        lp[i] = v;
        lmax = fmaxf(lmax, v);
    }

    // ---- block max over 32768 values ----
    #pragma unroll
    for (int off = 32; off >= 1; off >>= 1)
        lmax = fmaxf(lmax, __shfl_xor(lmax, off, 64));
    if ((t & 63) == 0) s_red[t >> 6] = lmax;
    __syncthreads();
    float m = s_red[0];
    #pragma unroll
    for (int k = 1; k < 8; ++k) m = fmaxf(m, s_red[k]);

    // ---- pass B: exp in registers, accumulate sum ----
    float lsum = 0.0f;
    #pragma unroll
    for (int i = 0; i < PT; ++i) {
        float e = __expf(lp[i] - m);
        lp[i] = e;
        lsum += e;
    }
    #pragma unroll
    for (int off = 32; off >= 1; off >>= 1)
        lsum += __shfl_xor(lsum, off, 64);
    __syncthreads();               // s_red reuse barrier
    if ((t & 63) == 0) s_red[t >> 6] = lsum;
    __syncthreads();
    float S = 0.0f;
    #pragma unroll
    for (int k = 0; k < 8; ++k) S += s_red[k];
    const float scale = 1.0f / (S + 1e-10f);

    // ---- pass C: single coalesced store of the whole output row ----
    float* op = out + (size_t)g * NPIX + t;
    #pragma unroll
    for (int i = 0; i < PT; ++i)
        op[i * BLOCK] = lp[i] * scale;
}

extern "C" void kernel_launch(void* const* d_in, const int* in_sizes, int n_in,
                              void* d_out, int out_size, void* d_ws, size_t ws_size,
                              hipStream_t stream) {
    const float* rep     = (const float*)d_in[0];
    const float* mean_W  = (const float*)d_in[1];
    const float* mean_b  = (const float*)d_in[2];
    const float* scale_W = (const float*)d_in[3];
    const float* scale_b = (const float*)d_in[4];
    float* out = (float*)d_out;

    hipLaunchKernelGGL(mvn_profile_kernel, dim3(NG), dim3(BLOCK), 0, stream,
                       rep, mean_W, mean_b, scale_W, scale_b, out);
}